// Round 1
// baseline (66.134 us; speedup 1.0000x reference)
//
#include <hip/hip_runtime.h>
#include <hip/hip_bf16.h>
#include <math.h>

#define HID   1024
#define HID3  3072
#define VOCAB 50257

// workspace layout (float offsets)
#define WS_X      0        // 1024
#define WS_GI     1024     // 3072
#define WS_GH     4096     // 3072
#define WS_HN     7168     // 1024
#define WS_LOGITS 8192     // 50257
#define WS_SCAL   58464    // 2 (m, lse)

__device__ __forceinline__ float wave_reduce_sum(float s) {
    #pragma unroll
    for (int off = 32; off; off >>= 1) s += __shfl_down(s, off, 64);
    return s;
}

// 1) x = relu(emb[token])
__global__ void prep_kernel(const int* __restrict__ token,
                            const float* __restrict__ emb,
                            float* __restrict__ x) {
    int j = threadIdx.x;                       // 1024 threads
    int tok = token[0];
    x[j] = fmaxf(emb[(size_t)tok * HID + j], 0.0f);
}

// 2) gi[row] = w_ih[row]·x + b_ih[row]; gh[row] = w_hh[row]·h + b_hh[row]
//    one wave per row, 6144 rows total (first 3072 = ih, next 3072 = hh)
__global__ void gates_kernel(const float* __restrict__ w_ih,
                             const float* __restrict__ w_hh,
                             const float* __restrict__ b_ih,
                             const float* __restrict__ b_hh,
                             const float* __restrict__ x,
                             const float* __restrict__ h,
                             float* __restrict__ gi,
                             float* __restrict__ gh) {
    int gwave = (blockIdx.x * blockDim.x + threadIdx.x) >> 6;
    if (gwave >= 2 * HID3) return;
    int lane = threadIdx.x & 63;
    bool isI = gwave < HID3;
    int row = isI ? gwave : gwave - HID3;
    const float4* w = (const float4*)((isI ? w_ih : w_hh) + (size_t)row * HID);
    const float4* v = (const float4*)(isI ? x : h);
    float s = 0.0f;
    #pragma unroll
    for (int it = 0; it < HID / 4 / 64; ++it) {
        float4 a = w[it * 64 + lane];
        float4 b = v[it * 64 + lane];
        s += a.x * b.x + a.y * b.y + a.z * b.z + a.w * b.w;
    }
    s = wave_reduce_sum(s);
    if (lane == 0) {
        if (isI) gi[row] = s + b_ih[row];
        else     gh[row] = s + b_hh[row];
    }
}

// 3) GRU pointwise -> h_new (to ws and to d_out tail)
__global__ void hnew_kernel(const float* __restrict__ gi,
                            const float* __restrict__ gh,
                            const float* __restrict__ h,
                            float* __restrict__ hn_ws,
                            float* __restrict__ hn_out) {
    int j = threadIdx.x;                       // 1024 threads
    float r = 1.0f / (1.0f + expf(-(gi[j] + gh[j])));
    float z = 1.0f / (1.0f + expf(-(gi[HID + j] + gh[HID + j])));
    float n = tanhf(gi[2 * HID + j] + r * gh[2 * HID + j]);
    float hv = h[j];
    float hn = (1.0f - z) * n + z * hv;
    hn_ws[j]  = hn;
    hn_out[j] = hn;
}

// 4) logits[row] = w_out[row]·h_new + b_out[row]; 4 rows/block, h_new in LDS
__global__ void logits_kernel(const float* __restrict__ w_out,
                              const float* __restrict__ b_out,
                              const float* __restrict__ hn,
                              float* __restrict__ logits) {
    __shared__ float4 lh[HID / 4];
    int t = threadIdx.x;                       // 256 threads = 4 waves
    lh[t] = ((const float4*)hn)[t];
    __syncthreads();
    int row = blockIdx.x * 4 + (t >> 6);
    if (row >= VOCAB) return;
    int lane = t & 63;
    const float4* w = (const float4*)(w_out + (size_t)row * HID);
    float s = 0.0f;
    #pragma unroll
    for (int it = 0; it < HID / 4 / 64; ++it) {
        float4 a = w[it * 64 + lane];
        float4 b = lh[it * 64 + lane];
        s += a.x * b.x + a.y * b.y + a.z * b.z + a.w * b.w;
    }
    s = wave_reduce_sum(s);
    if (lane == 0) logits[row] = s + b_out[row];
}

// 5) single-block max + log-sum-exp over VOCAB
__global__ void reduce_kernel(const float* __restrict__ logits,
                              float* __restrict__ scal) {
    __shared__ float wred[16];
    __shared__ float s_m;
    int t = threadIdx.x;                       // 1024 threads = 16 waves
    int lane = t & 63, wid = t >> 6;

    float m = -INFINITY;
    for (int i = t; i < VOCAB; i += 1024) m = fmaxf(m, logits[i]);
    #pragma unroll
    for (int off = 32; off; off >>= 1) m = fmaxf(m, __shfl_down(m, off, 64));
    if (lane == 0) wred[wid] = m;
    __syncthreads();
    if (t == 0) {
        float mm = wred[0];
        #pragma unroll
        for (int i = 1; i < 16; ++i) mm = fmaxf(mm, wred[i]);
        s_m = mm;
    }
    __syncthreads();
    m = s_m;

    float sum = 0.0f;
    for (int i = t; i < VOCAB; i += 1024) sum += expf(logits[i] - m);
    sum = wave_reduce_sum(sum);
    __syncthreads();                           // reuse wred safely
    if (lane == 0) wred[wid] = sum;
    __syncthreads();
    if (t == 0) {
        float tot = 0.0f;
        #pragma unroll
        for (int i = 0; i < 16; ++i) tot += wred[i];
        scal[0] = m;
        scal[1] = logf(tot);
    }
}

// 6) out[i] = logits[i] - m - lse
__global__ void final_kernel(const float* __restrict__ logits,
                             const float* __restrict__ scal,
                             float* __restrict__ out) {
    int i = blockIdx.x * 256 + threadIdx.x;
    if (i < VOCAB) out[i] = logits[i] - scal[0] - scal[1];
}

extern "C" void kernel_launch(void* const* d_in, const int* in_sizes, int n_in,
                              void* d_out, int out_size, void* d_ws, size_t ws_size,
                              hipStream_t stream) {
    const int*   token = (const int*)  d_in[0];
    const float* hidden= (const float*)d_in[1];   // [1,1,1024]
    const float* emb   = (const float*)d_in[2];
    const float* w_ih  = (const float*)d_in[3];
    const float* w_hh  = (const float*)d_in[4];
    const float* b_ih  = (const float*)d_in[5];
    const float* b_hh  = (const float*)d_in[6];
    const float* w_out = (const float*)d_in[7];
    const float* b_out = (const float*)d_in[8];

    float* ws  = (float*)d_ws;
    float* out = (float*)d_out;                   // [VOCAB logsoftmax][HID h_new]

    float* ws_x   = ws + WS_X;
    float* ws_gi  = ws + WS_GI;
    float* ws_gh  = ws + WS_GH;
    float* ws_hn  = ws + WS_HN;
    float* ws_lg  = ws + WS_LOGITS;
    float* ws_sc  = ws + WS_SCAL;

    prep_kernel<<<1, HID, 0, stream>>>(token, emb, ws_x);

    {   // 6144 rows, 1 wave/row, 4 waves/block
        int blocks = (2 * HID3 + 3) / 4;
        gates_kernel<<<blocks, 256, 0, stream>>>(w_ih, w_hh, b_ih, b_hh,
                                                 ws_x, hidden, ws_gi, ws_gh);
    }

    hnew_kernel<<<1, HID, 0, stream>>>(ws_gi, ws_gh, hidden, ws_hn, out + VOCAB);

    {   // VOCAB rows, 4 rows/block
        int blocks = (VOCAB + 3) / 4;
        logits_kernel<<<blocks, 256, 0, stream>>>(w_out, b_out, ws_hn, ws_lg);
    }

    reduce_kernel<<<1, 1024, 0, stream>>>(ws_lg, ws_sc);

    final_kernel<<<(VOCAB + 255) / 256, 256, 0, stream>>>(ws_lg, ws_sc, out);
}

// Round 2
// 47.662 us; speedup vs baseline: 1.3875x; 1.3875x over previous
//
#include <hip/hip_runtime.h>
#include <hip/hip_bf16.h>
#include <math.h>

#define HID   1024
#define HID3  3072
#define VOCAB 50257

#define LROWS_PER_BLOCK 16
#define LBLOCKS ((VOCAB + LROWS_PER_BLOCK - 1) / LROWS_PER_BLOCK)   // 3142

// workspace layout (float offsets)
#define WS_GI   0        // 3072
#define WS_GH   3072     // 3072
#define WS_HN   6144     // 1024
#define WS_PSUM 7168     // LBLOCKS partial sums
#define WS_SCAL 11264    // 1 (lse)

typedef float f32x4 __attribute__((ext_vector_type(4)));

__device__ __forceinline__ float wave_reduce_sum(float s) {
    #pragma unroll
    for (int off = 32; off; off >>= 1) s += __shfl_down(s, off, 64);
    return s;
}

// 1) gi[row] = w_ih[row]·relu(emb[tok]) + b_ih[row];  gh[row] = w_hh[row]·h + b_hh[row]
//    one wave per row, 6144 rows (first 3072 = ih, next 3072 = hh), 8 waves/block
__global__ void gates_kernel(const int* __restrict__ token,
                             const float* __restrict__ emb,
                             const float* __restrict__ w_ih,
                             const float* __restrict__ w_hh,
                             const float* __restrict__ b_ih,
                             const float* __restrict__ b_hh,
                             const float* __restrict__ h,
                             float* __restrict__ gi,
                             float* __restrict__ gh) {
    int gwave = (blockIdx.x * blockDim.x + threadIdx.x) >> 6;
    int lane  = threadIdx.x & 63;
    bool isI  = gwave < HID3;
    int row   = isI ? gwave : gwave - HID3;
    const f32x4* w = (const f32x4*)((isI ? w_ih : w_hh) + (size_t)row * HID);
    float s = 0.0f;
    if (isI) {
        const f32x4* e = (const f32x4*)(emb + (size_t)token[0] * HID);
        #pragma unroll
        for (int it = 0; it < HID / 4 / 64; ++it) {
            f32x4 a = __builtin_nontemporal_load(&w[it * 64 + lane]);
            f32x4 x = e[it * 64 + lane];
            s += a.x * fmaxf(x.x, 0.f) + a.y * fmaxf(x.y, 0.f)
               + a.z * fmaxf(x.z, 0.f) + a.w * fmaxf(x.w, 0.f);
        }
    } else {
        const f32x4* v = (const f32x4*)h;
        #pragma unroll
        for (int it = 0; it < HID / 4 / 64; ++it) {
            f32x4 a = __builtin_nontemporal_load(&w[it * 64 + lane]);
            f32x4 b = v[it * 64 + lane];
            s += a.x * b.x + a.y * b.y + a.z * b.z + a.w * b.w;
        }
    }
    s = wave_reduce_sum(s);
    if (lane == 0) {
        if (isI) gi[row] = s + b_ih[row];
        else     gh[row] = s + b_hh[row];
    }
}

// 2) GRU pointwise -> h_new (to ws and to d_out tail)
__global__ void hnew_kernel(const float* __restrict__ gi,
                            const float* __restrict__ gh,
                            const float* __restrict__ h,
                            float* __restrict__ hn_ws,
                            float* __restrict__ hn_out) {
    int j = threadIdx.x;                       // 1024 threads
    float r = 1.0f / (1.0f + expf(-(gi[j] + gh[j])));
    float z = 1.0f / (1.0f + expf(-(gi[HID + j] + gh[HID + j])));
    float n = tanhf(gi[2 * HID + j] + r * gh[2 * HID + j]);
    float hv = h[j];
    float hn = (1.0f - z) * n + z * hv;
    hn_ws[j]  = hn;
    hn_out[j] = hn;
}

// 3) logits[row] = w_out[row]·hn + b_out[row] -> out[row]; fused per-block sum(exp)
//    512 threads = 8 waves, 2 rows/wave = 16 rows/block
__global__ void logits_kernel(const float* __restrict__ w_out,
                              const float* __restrict__ b_out,
                              const float* __restrict__ hn,
                              float* __restrict__ out,
                              float* __restrict__ psum) {
    __shared__ f32x4 lh[HID / 4];
    __shared__ float wsum[8];
    int t = threadIdx.x;
    if (t < HID / 4) lh[t] = ((const f32x4*)hn)[t];
    __syncthreads();
    int lane = t & 63, w = t >> 6;
    int r0 = blockIdx.x * LROWS_PER_BLOCK + w * 2;
    int r1 = r0 + 1;
    // clamp so OOB waves load valid rows (results discarded)
    int c0 = r0 < VOCAB ? r0 : VOCAB - 1;
    int c1 = r1 < VOCAB ? r1 : VOCAB - 1;
    const f32x4* wa = (const f32x4*)(w_out + (size_t)c0 * HID);
    const f32x4* wb = (const f32x4*)(w_out + (size_t)c1 * HID);
    float s0 = 0.0f, s1 = 0.0f;
    #pragma unroll
    for (int it = 0; it < HID / 4 / 64; ++it) {
        f32x4 hv = lh[it * 64 + lane];
        f32x4 a = __builtin_nontemporal_load(&wa[it * 64 + lane]);
        f32x4 b = __builtin_nontemporal_load(&wb[it * 64 + lane]);
        s0 += a.x * hv.x + a.y * hv.y + a.z * hv.z + a.w * hv.w;
        s1 += b.x * hv.x + b.y * hv.y + b.z * hv.z + b.w * hv.w;
    }
    s0 = wave_reduce_sum(s0);
    s1 = wave_reduce_sum(s1);
    if (lane == 0) {
        float e = 0.0f;
        if (r0 < VOCAB) { float l0 = s0 + b_out[r0]; out[r0] = l0; e += expf(l0); }
        if (r1 < VOCAB) { float l1 = s1 + b_out[r1]; out[r1] = l1; e += expf(l1); }
        wsum[w] = e;
    }
    __syncthreads();
    if (t == 0) {
        float tot = 0.0f;
        #pragma unroll
        for (int i = 0; i < 8; ++i) tot += wsum[i];
        psum[blockIdx.x] = tot;
    }
}

// 4) lse = log(sum of block partials)  (max-free: logits are O(±7), exp safe in f32)
__global__ void reduce_kernel(const float* __restrict__ psum,
                              float* __restrict__ scal) {
    __shared__ float wred[16];
    int t = threadIdx.x;                       // 1024 threads
    float s = 0.0f;
    for (int i = t; i < LBLOCKS; i += 1024) s += psum[i];
    s = wave_reduce_sum(s);
    if ((t & 63) == 0) wred[t >> 6] = s;
    __syncthreads();
    if (t == 0) {
        float tot = 0.0f;
        #pragma unroll
        for (int i = 0; i < 16; ++i) tot += wred[i];
        scal[0] = logf(tot);
    }
}

// 5) out[i] -= lse (in place)
__global__ void final_kernel(float* __restrict__ out,
                             const float* __restrict__ scal) {
    int i = blockIdx.x * 256 + threadIdx.x;
    if (i < VOCAB) out[i] -= scal[0];
}

extern "C" void kernel_launch(void* const* d_in, const int* in_sizes, int n_in,
                              void* d_out, int out_size, void* d_ws, size_t ws_size,
                              hipStream_t stream) {
    const int*   token = (const int*)  d_in[0];
    const float* hidden= (const float*)d_in[1];   // [1,1,1024]
    const float* emb   = (const float*)d_in[2];
    const float* w_ih  = (const float*)d_in[3];
    const float* w_hh  = (const float*)d_in[4];
    const float* b_ih  = (const float*)d_in[5];
    const float* b_hh  = (const float*)d_in[6];
    const float* w_out = (const float*)d_in[7];
    const float* b_out = (const float*)d_in[8];

    float* ws  = (float*)d_ws;
    float* out = (float*)d_out;                   // [VOCAB logsoftmax][HID h_new]

    float* ws_gi = ws + WS_GI;
    float* ws_gh = ws + WS_GH;
    float* ws_hn = ws + WS_HN;
    float* ws_ps = ws + WS_PSUM;
    float* ws_sc = ws + WS_SCAL;

    // 6144 rows, 1 wave/row, 8 waves/block -> 768 blocks
    gates_kernel<<<768, 512, 0, stream>>>(token, emb, w_ih, w_hh, b_ih, b_hh,
                                          hidden, ws_gi, ws_gh);

    hnew_kernel<<<1, HID, 0, stream>>>(ws_gi, ws_gh, hidden, ws_hn, out + VOCAB);

    logits_kernel<<<LBLOCKS, 512, 0, stream>>>(w_out, b_out, ws_hn, out, ws_ps);

    reduce_kernel<<<1, 1024, 0, stream>>>(ws_ps, ws_sc);

    final_kernel<<<(VOCAB + 255) / 256, 256, 0, stream>>>(out, ws_sc);
}